// Round 5
// baseline (434.332 us; speedup 1.0000x reference)
//
#include <hip/hip_runtime.h>

typedef __attribute__((ext_vector_type(8))) short short8;
typedef __attribute__((ext_vector_type(4))) float f32x4;
union frag_u { short8 v; unsigned short u[8]; };

#define AS 328   // sA row stride in bf16 elems (tail L2 needs K=320, +8 pad)

__device__ __forceinline__ float bf2f(unsigned short b) {
  unsigned int u = ((unsigned int)b) << 16;
  float f; __builtin_memcpy(&f, &u, 4); return f;
}
__device__ __forceinline__ unsigned short f2bf(float f) {
  unsigned int u; __builtin_memcpy(&u, &f, 4);
  return (unsigned short)((u + 0x7FFFu + ((u >> 16) & 1u)) >> 16);
}
__device__ __forceinline__ unsigned short hi_of(float f) { return f2bf(f); }
__device__ __forceinline__ unsigned short lo_of(float f) {
  unsigned short h = f2bf(f); return f2bf(f - bf2f(h));
}
__device__ __forceinline__ float sigm(float x) {
  return __builtin_amdgcn_rcpf(1.f + __expf(-x));
}
__device__ __forceinline__ float tanh_(float x) {
  return 1.f - 2.f * __builtin_amdgcn_rcpf(1.f + __expf(2.f * x));
}

// sA(16 x K bf16, stride AS) @ W(K x N) -> sG[n][m] (stride 20)
// A-frag: lane holds A[m=lane&15][k=kc*32+quad*8+j]; B-frag: W[k][n=tile*16+(lane&15)]
// C/D: row m = quad*4+reg, col n = lane&15   [bench-verified: R2 pass, f32 variant]
template <typename GetB, typename GetW>
__device__ __forceinline__ void mfma_layer(const unsigned short* sA, float* sG,
    int wave, int col, int quad, int kc_n, int ntiles, int N, GetB getb, GetW getw)
{
  for (int tile = wave; tile < ntiles; tile += 4) {
    int n = tile * 16 + col;
    float b = (n < N) ? getb(n) : 0.f;
    f32x4 acc = {b, b, b, b};
    for (int kc = 0; kc < kc_n; ++kc) {
      short8 a = *(const short8*)&sA[col * AS + kc * 32 + quad * 8];
      frag_u w;
      #pragma unroll
      for (int j = 0; j < 8; ++j) {
        int k = kc * 32 + quad * 8 + j;
        w.u[j] = (n < N) ? getw(k, n) : (unsigned short)0;
      }
      acc = __builtin_amdgcn_mfma_f32_16x16x32_bf16(a, w.v, acc, 0, 0, 0);
    }
    *(f32x4*)&sG[n * 20 + quad * 4] = acc;
  }
}

// relu(sG) -> sA: hi at [0,N), lo at [loOff,loOff+N), zero to Kpad  [bench-verified R2]
__device__ __forceinline__ void relu_fill_lo(const float* sG, unsigned short* sA,
                                             int tid, int N, int loOff, int Kpad) {
  for (int idx = tid; idx < 16 * Kpad; idx += 256) {
    int m = idx & 15, n = idx >> 4;
    unsigned short v = 0;
    if (n < N)                          v = f2bf(fmaxf(sG[n * 20 + m], 0.f));
    else if (n >= loOff && n < loOff + N) v = lo_of(fmaxf(sG[(n - loOff) * 20 + m], 0.f));
    sA[m * AS + n] = v;
  }
}

__global__ __launch_bounds__(256) void value_net_kernel(
    const float* __restrict__ state,
    const float* __restrict__ wih, const float* __restrict__ whh,
    const float* __restrict__ bih, const float* __restrict__ bhh,
    const float* __restrict__ w1, const float* __restrict__ b1,
    const float* __restrict__ w2, const float* __restrict__ b2,
    const float* __restrict__ w3, const float* __restrict__ b3,
    const float* __restrict__ w4, const float* __restrict__ b4,
    float* __restrict__ out)
{
  // LSTM A cols (K=192): [x_hi 0..6 | x_lo 7..13 | x_hi 14..20 | h_hi 21..70 |
  //                       h_lo 71..120 | h_hi 121..170 | zero ..191]
  // paired W rows: [wih_hi | wih_hi | wih_lo | whh_hi | whh_hi | whh_lo]  (tri-product)
  __shared__ __align__(16) unsigned short sA[16 * AS];      // 10.25 KB
  __shared__ __align__(16) float sG[160 * 20];              // 12.5 KB (tail only)
  __shared__ __align__(16) unsigned int sX[16 * 64 * 7];    // 28 KB packed hi<<16|lo

  const int tid  = threadIdx.x;
  const int wave = tid >> 6;
  const int lane = tid & 63;
  const int col  = lane & 15;
  const int quad = lane >> 4;
  const int r0   = blockIdx.x * 16;

  // ---- coalesced staging: whole 16-row state slab -> packed x in LDS ----
  {
    const float* base = state + (size_t)r0 * 832;
    #pragma unroll
    for (int i = 0; i < 52; ++i) {
      int idx = tid + i * 256;                 // 52*256 = 13312 = 16*832 exactly
      float v = base[idx];
      int row = idx / 832;
      int rem = idx - row * 832;
      int t = rem / 13;
      int d = rem - t * 13;
      if (d >= 6) {
        unsigned short h = f2bf(v);
        unsigned short l = f2bf(v - bf2f(h));
        sX[(row * 64 + t) * 7 + (d - 6)] = ((unsigned int)h << 16) | l;
      }
    }
  }
  // ---- zero sA (h0 = 0 and all padding) ----
  {
    unsigned int* a32 = (unsigned int*)sA;
    #pragma unroll
    for (int i = 0; i < 11; ++i) {
      int idx = tid + i * 256;
      if (idx < (16 * AS) / 2) a32[idx] = 0;
    }
  }

  // ---- persistent gate-separated LSTM weight fragments (hi/lo from f32) ----
  // wave owns units uu = wave*16+col (valid uu<50); G[g] = gate g (i,f,g,o) cols g*50+uu
  const int  uu  = wave * 16 + col;
  const bool uok = uu < 50;
  frag_u wf[4][6];
  float  wb[4];
  #pragma unroll
  for (int g = 0; g < 4; ++g) {
    int c = g * 50 + uu;
    #pragma unroll
    for (int kc = 0; kc < 6; ++kc) {
      #pragma unroll
      for (int j = 0; j < 8; ++j) {
        int k = kc * 32 + quad * 8 + j;
        unsigned short w = 0;
        if (uok) {
          if (k < 7)        w = hi_of(wih[k * 200 + c]);
          else if (k < 14)  w = hi_of(wih[(k - 7) * 200 + c]);
          else if (k < 21)  w = lo_of(wih[(k - 14) * 200 + c]);
          else if (k < 71)  w = hi_of(whh[(k - 21) * 200 + c]);
          else if (k < 121) w = hi_of(whh[(k - 71) * 200 + c]);
          else if (k < 171) w = lo_of(whh[(k - 121) * 200 + c]);
        }
        wf[g][kc].u[j] = w;
      }
    }
    wb[g] = uok ? (bih[c] + bhh[c]) : 0.f;
  }

  const int  xm = tid / 7, xd = tid - (tid / 7) * 7;
  const bool isx = tid < 112;
  float cst[4] = {0.f, 0.f, 0.f, 0.f};

  __syncthreads();
  if (isx) {   // x_0
    unsigned int w = sX[(xm * 64 + 0) * 7 + xd];
    unsigned short h = (unsigned short)(w >> 16), l = (unsigned short)(w & 0xffffu);
    sA[xm * AS + xd] = h; sA[xm * AS + 7 + xd] = l; sA[xm * AS + 14 + xd] = h;
  }
  __syncthreads();

  // ---- LSTM: 64 steps, 2-barrier protocol (read -> bar -> write -> bar) ----
  for (int t = 0; t < 64; ++t) {
    short8 a[6];
    #pragma unroll
    for (int kc = 0; kc < 6; ++kc)
      a[kc] = *(const short8*)&sA[col * AS + kc * 32 + quad * 8];

    f32x4 G[4];
    #pragma unroll
    for (int g = 0; g < 4; ++g) {
      float b = wb[g];
      f32x4 acc = {b, b, b, b};
      #pragma unroll
      for (int kc = 0; kc < 6; ++kc)
        acc = __builtin_amdgcn_mfma_f32_16x16x32_bf16(a[kc], wf[g][kc].v, acc, 0, 0, 0);
      G[g] = acc;
    }
    __syncthreads();   // all sA reads done before any write

    #pragma unroll
    for (int r = 0; r < 4; ++r) {
      float si = sigm(G[0][r]);
      float sf = sigm(G[1][r]);
      float tg = tanh_(G[2][r]);
      float so = sigm(G[3][r]);
      float cc = sf * cst[r] + si * tg;
      cst[r] = cc;
      float h = so * tanh_(cc);
      if (uok) {
        int m = quad * 4 + r;
        unsigned short hb = f2bf(h);
        unsigned short hl = f2bf(h - bf2f(hb));
        if (t < 63) {                       // LSTM layout
          sA[m * AS + 21 + uu]  = hb;
          sA[m * AS + 71 + uu]  = hl;
          sA[m * AS + 121 + uu] = hb;
        } else {                            // final h straight into tail layout
          sA[m * AS + 6 + uu]  = hb;
          sA[m * AS + 62 + uu] = hl;
        }
      }
    }
    if (isx && t < 63) {
      unsigned int w = sX[(xm * 64 + (t + 1)) * 7 + xd];
      unsigned short h = (unsigned short)(w >> 16), l = (unsigned short)(w & 0xffffu);
      sA[xm * AS + xd] = h; sA[xm * AS + 7 + xd] = l; sA[xm * AS + 14 + xd] = h;
    }
    __syncthreads();
  }

  // ---- tail prep: joint = [self_hi 0..5 | h_hi 6..55 | self_lo 56..61 | h_lo 62..111 | 0 ..127]
  {
    int m = tid >> 4;
    sA[m * AS + 112 + (tid & 15)] = 0;      // zero stale cols 112..127
  }
  if (tid < 96) {
    int m = tid / 6, d = tid - (tid / 6) * 6;
    float f = state[(size_t)(r0 + m) * 832 + d];
    unsigned short h = f2bf(f);
    sA[m * AS + d]      = h;
    sA[m * AS + 56 + d] = f2bf(f - bf2f(h));
  }
  __syncthreads();

  // L1: K=112->128; w1 rows 0..5 self, 6..55 h; lo-halves reuse same hi weights
  mfma_layer(sA, sG, wave, col, quad, 4, 10, 150,
    [&](int n) { return b1[n]; },
    [&](int k, int n) -> unsigned short {
      if (k < 56)  return hi_of(w1[k * 150 + n]);
      if (k < 112) return hi_of(w1[(k - 56) * 150 + n]);
      return (unsigned short)0;
    });
  __syncthreads();
  relu_fill_lo(sG, sA, tid, 150, 150, 320);
  __syncthreads();

  // L2: K=300->320
  mfma_layer(sA, sG, wave, col, quad, 10, 7, 100,
    [&](int n) { return b2[n]; },
    [&](int k, int n) -> unsigned short {
      if (k < 150) return hi_of(w2[k * 100 + n]);
      if (k < 300) return hi_of(w2[(k - 150) * 100 + n]);
      return (unsigned short)0;
    });
  __syncthreads();
  relu_fill_lo(sG, sA, tid, 100, 100, 224);
  __syncthreads();

  // L3: K=200->224
  mfma_layer(sA, sG, wave, col, quad, 7, 7, 100,
    [&](int n) { return b3[n]; },
    [&](int k, int n) -> unsigned short {
      if (k < 100) return hi_of(w3[k * 100 + n]);
      if (k < 200) return hi_of(w3[(k - 100) * 100 + n]);
      return (unsigned short)0;
    });
  __syncthreads();

  // L4: relu(sG) @ w4 + b4, f32, 16-lane shuffle reduce; f32 output
  {
    int m = tid >> 4, j0 = tid & 15;
    float s = 0.f;
    for (int j = j0; j < 100; j += 16)
      s += fmaxf(sG[j * 20 + m], 0.f) * w4[j];
    s += __shfl_xor(s, 8); s += __shfl_xor(s, 4);
    s += __shfl_xor(s, 2); s += __shfl_xor(s, 1);
    if (j0 == 0) out[r0 + m] = s + b4[0];
  }
}

extern "C" void kernel_launch(void* const* d_in, const int* in_sizes, int n_in,
                              void* d_out, int out_size, void* d_ws, size_t ws_size,
                              hipStream_t stream) {
  (void)in_sizes; (void)n_in; (void)d_ws; (void)ws_size; (void)out_size;
  // d_in[1..10] (mlp1_* / attn_*) are dead code in the reference — unused.
  // R2 bench: passing dispatch had LDS=27136B == the F32 template variant, and
  // FETCH 14.5MB == f32 partial-state reads -> ALL BUFFERS ARE FLOAT32.
  const float* state = (const float*)d_in[0];
  const float* wih = (const float*)d_in[11];
  const float* whh = (const float*)d_in[12];
  const float* bih = (const float*)d_in[13];
  const float* bhh = (const float*)d_in[14];
  const float* w1  = (const float*)d_in[15];
  const float* b1  = (const float*)d_in[16];
  const float* w2  = (const float*)d_in[17];
  const float* b2  = (const float*)d_in[18];
  const float* w3  = (const float*)d_in[19];
  const float* b3  = (const float*)d_in[20];
  const float* w4  = (const float*)d_in[21];
  const float* b4  = (const float*)d_in[22];

  value_net_kernel<<<dim3(512), dim3(256), 0, stream>>>(
      state, wih, whh, bih, bhh, w1, b1, w2, b2, w3, b3, w4, b4,
      (float*)d_out);
}